// Round 4
// baseline (126.815 us; speedup 1.0000x reference)
//
#include <hip/hip_runtime.h>
#include <hip/hip_bf16.h>
#include <math.h>

// Problem constants
#define NB 8
#define LN 4096       // sequence length L
#define NH 8
#define NE 64
#define NC 512        // NH*NE channels
#define NM 64         // modes kept
#define LMASK 4095

typedef short s16x8 __attribute__((ext_vector_type(8)));
typedef float f32x4 __attribute__((ext_vector_type(4)));

// ws layout (in floats):
//  egf : bf16[128kc][8mt][64][8]        @ 0        (1 MB)  fwd twiddle A-fragments
//  tf  : bf16[4kk][256lt][64][8]        @ 262144   (1 MB)  inv twiddle B-fragments
//  gf  : bf16[8b][4kk][32ct][64][8]     @ 524288   (1 MB)  mixed-spectrum A-fragments
//  xp  : f32[8ks][8b][8h][64i][128m±]   @ 786432   (16 MB) partial fwd GEMM outputs
//  xs  : f32[8b][8h][64i][128m±]        @ 4980736  (2 MB)  ks-summed spectrum
#define WS_EGF 0
#define WS_TF  262144
#define WS_GF  524288
#define WS_XP  786432
#define WS_XS  4980736

static __device__ __forceinline__ unsigned short bf16bits(float f) {
    __hip_bfloat16 b = __float2bfloat16(f);
    return *reinterpret_cast<unsigned short*>(&b);
}

// Both twiddle tables in one launch. Blocks 0..255: egf (fwd A-frags);
// blocks 256..511: tf (inv B-frags).
__global__ __launch_bounds__(256) void k_tables(unsigned short* __restrict__ egf,
                                                unsigned short* __restrict__ tfp) {
    const int bid = blockIdx.x;
    const int s = (bid & 255) * 256 + threadIdx.x;   // 0..65535
    const int lane = s & 63;
    unsigned short v[8];
    if (bid < 256) {
        // E[2m][l]=cos, E[2m+1][l]=-sin ; slot s=(kc<<9)|(mt<<6)|lane
        int mt = (s >> 6) & 7, kc = s >> 9;
        int r = lane & 15, kg = lane >> 4;
        int mpm = mt * 16 + r;
        int m = mpm >> 1, isim = mpm & 1;
        #pragma unroll
        for (int j = 0; j < 8; ++j) {
            int l = kc * 32 + kg * 8 + j;
            int tw = (m * l) & LMASK;
            float ang = (6.283185307179586f / 4096.0f) * (float)tw;
            v[j] = bf16bits(isim ? -sinf(ang) : cosf(ang));
        }
    } else {
        // T[l][2m]=cos, T[l][2m+1]=sin ; slot s=(kk<<14)|(lt<<6)|lane
        int lt = (s >> 6) & 255, kk = s >> 14;
        int l = lt * 16 + (lane & 15);
        int khi = (lane >> 4) * 8;
        #pragma unroll
        for (int j = 0; j < 8; ++j) {
            int mp = kk * 32 + khi + j;
            int m = mp >> 1;
            int tw = (m * l) & LMASK;
            float ang = (6.283185307179586f / 4096.0f) * (float)tw;
            v[j] = bf16bits((mp & 1) ? sinf(ang) : cosf(ang));
        }
    }
    uint4 pk;
    pk.x = (unsigned)v[0] | ((unsigned)v[1] << 16);
    pk.y = (unsigned)v[2] | ((unsigned)v[3] << 16);
    pk.z = (unsigned)v[4] | ((unsigned)v[5] << 16);
    pk.w = (unsigned)v[6] | ((unsigned)v[7] << 16);
    unsigned short* dst = (bid < 256) ? egf : tfp;
    *reinterpret_cast<uint4*>(dst + (size_t)s * 8) = pk;
}

// Fused stage 1: reads raw fp32 q, stages bf16 tile in LDS, MFMAs against egf.
// grid (8 ks, 8 h, 8 b), block 256 = 4 waves. Wave w owns i-subtile nt=w (16 i),
// computes all 128 m± rows (8 MFMA/iter). K_block = 512 l = 16 iters of 32 l.
__global__ __launch_bounds__(256, 2) void k_fs1(const float* __restrict__ q,
                                                const unsigned short* __restrict__ egf,
                                                float* __restrict__ xp) {
    // LDS tile: [4 st][32 l][16 i] bf16 = 4KB. st = i>>4.
    __shared__ unsigned short tile[2048];
    const int ks = blockIdx.x, h = blockIdx.y, b = blockIdx.z;
    const int tid = threadIdx.x;
    const int w = tid >> 6, lane = tid & 63;

    // staging: thread loads 8 consecutive i at row sl
    const int sl = tid >> 3;            // 0..31
    const int sc = tid & 7;             // i-chunk (8 i each)
    const float* qbase = q + (((size_t)b * LN + (size_t)ks * 512) * NH + h) * NE + sc * 8;
    uint4* tq4 = reinterpret_cast<uint4*>(tile);
    const int wslot = (sc >> 1) * 64 + sl * 2 + (sc & 1);

    // B-fragment read base for this wave's subtile
    const unsigned short* tp = tile + w * 512 + (lane >> 4) * 128 + (lane & 15);

    f32x4 acc[8];
    #pragma unroll
    for (int mt = 0; mt < 8; ++mt) acc[mt] = (f32x4)(0.0f);

#define FS1_LOAD(T, A, B2)                                                        \
    {                                                                             \
        const float* p_ = qbase + ((size_t)(T) * 32 + sl) * NC;                   \
        A  = *reinterpret_cast<const float4*>(p_);                                \
        B2 = *reinterpret_cast<const float4*>(p_ + 4);                            \
    }

    float4 qa, qb_;
    FS1_LOAD(0, qa, qb_)

    for (int t = 0; t < 16; ++t) {
        // pack current rows to bf16, write tile
        uint4 pk;
        pk.x = (unsigned)bf16bits(qa.x)  | ((unsigned)bf16bits(qa.y)  << 16);
        pk.y = (unsigned)bf16bits(qa.z)  | ((unsigned)bf16bits(qa.w)  << 16);
        pk.z = (unsigned)bf16bits(qb_.x) | ((unsigned)bf16bits(qb_.y) << 16);
        pk.w = (unsigned)bf16bits(qb_.z) | ((unsigned)bf16bits(qb_.w) << 16);
        tq4[wslot] = pk;
        __syncthreads();

        float4 na, nb;
        if (t < 15) FS1_LOAD(t + 1, na, nb)

        // A fragments (L2-resident, fragment-formatted)
        const unsigned short* ep = egf + (((size_t)(ks * 16 + t) * 8) * 64 + lane) * 8;
        s16x8 af[8];
        #pragma unroll
        for (int mt = 0; mt < 8; ++mt)
            af[mt] = *reinterpret_cast<const s16x8*>(ep + (size_t)mt * 512);

        // B fragment from LDS (k-major gather)
        s16x8 bfr;
        #pragma unroll
        for (int j = 0; j < 8; ++j) bfr[j] = (short)tp[j * 16];

        #pragma unroll
        for (int mt = 0; mt < 8; ++mt)
            acc[mt] = __builtin_amdgcn_mfma_f32_16x16x32_bf16(af[mt], bfr, acc[mt], 0, 0, 0);
        __syncthreads();

        if (t < 15) { qa = na; qb_ = nb; }
    }
#undef FS1_LOAD

    // Epilogue: D row = m±-local = (lane>>4)*4 + reg, col = i-local = lane&15.
    const int i = w * 16 + (lane & 15);
    float* xpb = xp + ((size_t)ks * 64 + b * 8 + h) * (64 * 128) + (size_t)i * 128 + (lane >> 4) * 4;
    #pragma unroll
    for (int mt = 0; mt < 8; ++mt)
        *reinterpret_cast<f32x4*>(xpb + mt * 16) = acc[mt];
}

// Sum the 8 K-split partials.
__global__ __launch_bounds__(256) void k_presum(const float* __restrict__ xp,
                                                float* __restrict__ xs) {
    int e = blockIdx.x * 256 + threadIdx.x;      // 0..524287
    float s = 0.f;
    #pragma unroll
    for (int ks = 0; ks < 8; ++ks) s += xp[(size_t)ks * 524288 + e];
    xs[e] = s;
}

// Stage 2: complex channel mix. grid (8 og, 8 h), block 512: m = tx&63, osub = tx>>6.
// b-loop inside so w1/w2 (16 MB) are read exactly once. Writes G bf16 A-fragments.
__global__ __launch_bounds__(512) void k_stage2(const float* __restrict__ w1,
                                                const float* __restrict__ w2,
                                                const float* __restrict__ xs,
                                                unsigned short* __restrict__ gf) {
    const int og = blockIdx.x;              // 0..7
    const int h  = blockIdx.y;
    const int m    = threadIdx.x & 63;
    const int osub = threadIdx.x >> 6;      // 0..7
    const int o = og * 8 + osub;

    float re[8], im[8];
    #pragma unroll
    for (int b = 0; b < 8; ++b) { re[b] = 0.f; im[b] = 0.f; }

    const float2* xsf = reinterpret_cast<const float2*>(xs);
    const float* w1p = w1 + (size_t)h * NE * NE * NM + (size_t)o * NM + m;
    const float* w2p = w2 + (size_t)h * NE * NE * NM + (size_t)o * NM + m;

    #pragma unroll 2
    for (int i = 0; i < NE; ++i) {
        float wr = w1p[(size_t)i * (NE * NM)];
        float wi = w2p[(size_t)i * (NE * NM)];
        #pragma unroll
        for (int b = 0; b < 8; ++b) {
            float2 xv = xsf[((size_t)(b * 8 + h) * 64 + i) * 64 + m];  // (re, im)
            re[b] = fmaf(xv.x, wr, fmaf(-xv.y, wi, re[b]));
            im[b] = fmaf(xv.x, wi, fmaf( xv.y, wr, im[b]));
        }
    }

    const float s = (m == 0 ? 1.0f : 2.0f) / (float)LN;  // irfft fold: (2-delta_m0)/L
    // G[2m][c] = s*re, G[2m+1][c] = -s*im, A-fragment layout:
    // slot = ((b*4 + (m>>4))*32 + (c>>4))*64 + ((m&15)>>2)*16 + (c&15), elems ((m&3)<<1)+{0,1}
    const int kk  = m >> 4;
    const int khi = ((m & 15) >> 2) * 16;
    const int jj  = (m & 3) << 1;
    const int c = h * 64 + o;
    #pragma unroll
    for (int b = 0; b < 8; ++b) {
        size_t slot = (((size_t)b * 4 + kk) * 32 + (c >> 4)) * 64 + khi + (c & 15);
        unsigned int pk = (unsigned)bf16bits(re[b] * s) | ((unsigned)bf16bits(-im[b] * s) << 16);
        *reinterpret_cast<unsigned int*>(gf + slot * 8 + jj) = pk;
    }
}

// Stage 3 MFMA: per b: out[l][c] = sum_mp T[l][mp] * G[mp][c].  M=c(128/block), N=l(64/block), K=128.
// grid (64 lb, 4 cb, 8 b), block 256 = 4 waves; wave w owns c-quarter [w*32, w*32+32).
// Zero LDS / zero barriers; both operand tables stream from L2.
__global__ __launch_bounds__(256, 2) void k_s3(const unsigned short* __restrict__ gf,
                                               const unsigned short* __restrict__ tfp,
                                               float* __restrict__ out) {
    const int lb = blockIdx.x;   // l base = lb*64
    const int cb = blockIdx.y;   // c base = cb*128
    const int b  = blockIdx.z;
    const int tid = threadIdx.x;
    const int w = tid >> 6, lane = tid & 63;

    const unsigned short* ga = gf + ((((size_t)b * 4) * 32 + cb * 8 + w * 2) * 64 + lane) * 8;
    const unsigned short* tb = tfp + (((size_t)lb * 4) * 64 + lane) * 8;

    f32x4 acc[2][4] = {};
    s16x8 af[3][2], bf[3][4];

#define S3_LOAD(T, SLOT)                                                          \
    {                                                                             \
        const unsigned short* gp_ = ga + (size_t)(T) * (32 * 64 * 8);             \
        const unsigned short* tp_ = tb + (size_t)(T) * (256 * 64 * 8);            \
        af[SLOT][0] = *reinterpret_cast<const s16x8*>(gp_);                       \
        af[SLOT][1] = *reinterpret_cast<const s16x8*>(gp_ + 64 * 8);              \
        bf[SLOT][0] = *reinterpret_cast<const s16x8*>(tp_);                       \
        bf[SLOT][1] = *reinterpret_cast<const s16x8*>(tp_ + 64 * 8);              \
        bf[SLOT][2] = *reinterpret_cast<const s16x8*>(tp_ + 2 * 64 * 8);          \
        bf[SLOT][3] = *reinterpret_cast<const s16x8*>(tp_ + 3 * 64 * 8);          \
    }

    S3_LOAD(0, 0)
    S3_LOAD(1, 1)

    #pragma unroll
    for (int t = 0; t < 4; ++t) {
        const int slot = t % 3;
        if (t + 2 < 4) { const int ns = (t + 2) % 3; S3_LOAD(t + 2, ns) }
        #pragma unroll
        for (int mi = 0; mi < 2; ++mi)
            #pragma unroll
            for (int ni = 0; ni < 4; ++ni)
                acc[mi][ni] = __builtin_amdgcn_mfma_f32_16x16x32_bf16(
                    af[slot][mi], bf[slot][ni], acc[mi][ni], 0, 0, 0);
    }
#undef S3_LOAD

    // D[row=c_local][col=l_local]; f32x4 regs span 4 consecutive c.
    const int c0 = cb * 128 + w * 32 + (lane >> 4) * 4;
    const int l0 = lb * 64 + (lane & 15);
    #pragma unroll
    for (int mi = 0; mi < 2; ++mi)
        #pragma unroll
        for (int ni = 0; ni < 4; ++ni) {
            float* op = out + ((size_t)b * LN + l0 + ni * 16) * NC + c0 + mi * 16;
            *reinterpret_cast<f32x4*>(op) = acc[mi][ni];
        }
}

extern "C" void kernel_launch(void* const* d_in, const int* in_sizes, int n_in,
                              void* d_out, int out_size, void* d_ws, size_t ws_size,
                              hipStream_t stream) {
    const float* q  = (const float*)d_in[0];
    // d_in[1] (k) and d_in[2] (v) are unused by the reference
    const float* w1 = (const float*)d_in[3];
    const float* w2 = (const float*)d_in[4];
    float* out = (float*)d_out;
    float* ws  = (float*)d_ws;

    unsigned short* egf = (unsigned short*)(ws + WS_EGF);
    unsigned short* tfp = (unsigned short*)(ws + WS_TF);
    unsigned short* gf  = (unsigned short*)(ws + WS_GF);
    float*          xp  = ws + WS_XP;
    float*          xs  = ws + WS_XS;

    k_tables<<<512, 256, 0, stream>>>(egf, tfp);
    k_fs1<<<dim3(8, NH, NB), 256, 0, stream>>>(q, egf, xp);
    k_presum<<<2048, 256, 0, stream>>>(xp, xs);
    k_stage2<<<dim3(8, NH), 512, 0, stream>>>(w1, w2, xs, gf);
    k_s3<<<dim3(64, 4, NB), 256, 0, stream>>>(gf, tfp, out);
}

// Round 5
// 85.947 us; speedup vs baseline: 1.4755x; 1.4755x over previous
//
#include <hip/hip_runtime.h>
#include <hip/hip_bf16.h>
#include <math.h>

// Problem constants
#define NB 8
#define LN 4096       // sequence length L
#define NH 8
#define NE 64
#define NC 512        // NH*NE channels
#define NM 64         // modes kept
#define LMASK 4095

typedef short s16x8 __attribute__((ext_vector_type(8)));
typedef float f32x4 __attribute__((ext_vector_type(4)));

// ws layout (in floats):
//  egf : bf16[128kc][8mt][64][8]        @ 0        (1 MB)  fwd twiddle A-fragments
//  tf  : bf16[4kk][256lt][64][8]        @ 262144   (1 MB)  inv twiddle B-fragments
//  gf  : bf16[8b][4kk][32ct][64][8]     @ 524288   (1 MB)  mixed-spectrum A-fragments
//  xp  : f32[8ks][8b][8h][64i][128m±]   @ 786432   (16 MB) partial fwd GEMM outputs
//  xs  : f32[8b][8h][64i][128m±]        @ 4980736  (2 MB)  ks-summed spectrum
//  part: f32[4is][8b][512c][64m][2]     @ 5505024  (8 MB)  stage2 i-split partials
#define WS_EGF 0
#define WS_TF  262144
#define WS_GF  524288
#define WS_XP  786432
#define WS_XS  4980736
#define WS_PART 5505024

static __device__ __forceinline__ unsigned short bf16bits(float f) {
    __hip_bfloat16 b = __float2bfloat16(f);
    return *reinterpret_cast<unsigned short*>(&b);
}

// Both twiddle tables in one launch. Blocks 0..255: egf (fwd A-frags);
// blocks 256..511: tf (inv B-frags).
__global__ __launch_bounds__(256) void k_tables(unsigned short* __restrict__ egf,
                                                unsigned short* __restrict__ tfp) {
    const int bid = blockIdx.x;
    const int s = (bid & 255) * 256 + threadIdx.x;   // 0..65535
    const int lane = s & 63;
    unsigned short v[8];
    if (bid < 256) {
        // E[2m][l]=cos, E[2m+1][l]=-sin ; slot s=(kc<<9)|(mt<<6)|lane
        int mt = (s >> 6) & 7, kc = s >> 9;
        int r = lane & 15, kg = lane >> 4;
        int mpm = mt * 16 + r;
        int m = mpm >> 1, isim = mpm & 1;
        #pragma unroll
        for (int j = 0; j < 8; ++j) {
            int l = kc * 32 + kg * 8 + j;
            int tw = (m * l) & LMASK;
            float ang = (6.283185307179586f / 4096.0f) * (float)tw;
            v[j] = bf16bits(isim ? -sinf(ang) : cosf(ang));
        }
    } else {
        // T[l][2m]=cos, T[l][2m+1]=sin ; slot s=(kk<<14)|(lt<<6)|lane
        int lt = (s >> 6) & 255, kk = s >> 14;
        int l = lt * 16 + (lane & 15);
        int khi = (lane >> 4) * 8;
        #pragma unroll
        for (int j = 0; j < 8; ++j) {
            int mp = kk * 32 + khi + j;
            int m = mp >> 1;
            int tw = (m * l) & LMASK;
            float ang = (6.283185307179586f / 4096.0f) * (float)tw;
            v[j] = bf16bits((mp & 1) ? sinf(ang) : cosf(ang));
        }
    }
    uint4 pk;
    pk.x = (unsigned)v[0] | ((unsigned)v[1] << 16);
    pk.y = (unsigned)v[2] | ((unsigned)v[3] << 16);
    pk.z = (unsigned)v[4] | ((unsigned)v[5] << 16);
    pk.w = (unsigned)v[6] | ((unsigned)v[7] << 16);
    unsigned short* dst = (bid < 256) ? egf : tfp;
    *reinterpret_cast<uint4*>(dst + (size_t)s * 8) = pk;
}

// Fused stage 1: reads raw fp32 q, stages bf16 tile in LDS, MFMAs against egf.
// grid (8 ks, 8 h, 8 b), block 256 = 4 waves. Wave w owns i-subtile nt=w (16 i),
// computes all 128 m± rows (8 MFMA/iter). K_block = 512 l = 16 iters of 32 l.
__global__ __launch_bounds__(256, 2) void k_fs1(const float* __restrict__ q,
                                                const unsigned short* __restrict__ egf,
                                                float* __restrict__ xp) {
    // LDS tile: [4 st][32 l][16 i] bf16 = 4KB. st = i>>4.
    __shared__ unsigned short tile[2048];
    const int ks = blockIdx.x, h = blockIdx.y, b = blockIdx.z;
    const int tid = threadIdx.x;
    const int w = tid >> 6, lane = tid & 63;

    // staging: thread loads 8 consecutive i at row sl
    const int sl = tid >> 3;            // 0..31
    const int sc = tid & 7;             // i-chunk (8 i each)
    const float* qbase = q + (((size_t)b * LN + (size_t)ks * 512) * NH + h) * NE + sc * 8;
    uint4* tq4 = reinterpret_cast<uint4*>(tile);
    const int wslot = (sc >> 1) * 64 + sl * 2 + (sc & 1);

    // B-fragment read base for this wave's subtile
    const unsigned short* tp = tile + w * 512 + (lane >> 4) * 128 + (lane & 15);

    f32x4 acc[8];
    #pragma unroll
    for (int mt = 0; mt < 8; ++mt) acc[mt] = (f32x4)(0.0f);

#define FS1_LOAD(T, A, B2)                                                        \
    {                                                                             \
        const float* p_ = qbase + ((size_t)(T) * 32 + sl) * NC;                   \
        A  = *reinterpret_cast<const float4*>(p_);                                \
        B2 = *reinterpret_cast<const float4*>(p_ + 4);                            \
    }

    float4 qa, qb_;
    FS1_LOAD(0, qa, qb_)

    for (int t = 0; t < 16; ++t) {
        // pack current rows to bf16, write tile
        uint4 pk;
        pk.x = (unsigned)bf16bits(qa.x)  | ((unsigned)bf16bits(qa.y)  << 16);
        pk.y = (unsigned)bf16bits(qa.z)  | ((unsigned)bf16bits(qa.w)  << 16);
        pk.z = (unsigned)bf16bits(qb_.x) | ((unsigned)bf16bits(qb_.y) << 16);
        pk.w = (unsigned)bf16bits(qb_.z) | ((unsigned)bf16bits(qb_.w) << 16);
        tq4[wslot] = pk;
        __syncthreads();

        float4 na, nb;
        if (t < 15) FS1_LOAD(t + 1, na, nb)

        // A fragments (L2-resident, fragment-formatted)
        const unsigned short* ep = egf + (((size_t)(ks * 16 + t) * 8) * 64 + lane) * 8;
        s16x8 af[8];
        #pragma unroll
        for (int mt = 0; mt < 8; ++mt)
            af[mt] = *reinterpret_cast<const s16x8*>(ep + (size_t)mt * 512);

        // B fragment from LDS (k-major gather)
        s16x8 bfr;
        #pragma unroll
        for (int j = 0; j < 8; ++j) bfr[j] = (short)tp[j * 16];

        #pragma unroll
        for (int mt = 0; mt < 8; ++mt)
            acc[mt] = __builtin_amdgcn_mfma_f32_16x16x32_bf16(af[mt], bfr, acc[mt], 0, 0, 0);
        __syncthreads();

        if (t < 15) { qa = na; qb_ = nb; }
    }
#undef FS1_LOAD

    // Epilogue: D row = m±-local = (lane>>4)*4 + reg, col = i-local = lane&15.
    const int i = w * 16 + (lane & 15);
    float* xpb = xp + ((size_t)ks * 64 + b * 8 + h) * (64 * 128) + (size_t)i * 128 + (lane >> 4) * 4;
    #pragma unroll
    for (int mt = 0; mt < 8; ++mt)
        *reinterpret_cast<f32x4*>(xpb + mt * 16) = acc[mt];
}

// Sum the 8 K-split partials.
__global__ __launch_bounds__(256) void k_presum(const float* __restrict__ xp,
                                                float* __restrict__ xs) {
    int e = blockIdx.x * 256 + threadIdx.x;      // 0..524287
    float s = 0.f;
    #pragma unroll
    for (int ks = 0; ks < 8; ++ks) s += xp[(size_t)ks * 524288 + e];
    xs[e] = s;
}

// Stage 2a: i-split channel mix. grid (4 isplit, 16 og, 8 h), block 256.
// Thread: osub = tid>>6 (0..3), m = tid&63; o = og*4+osub. 16 i per block,
// all 8 b in registers -> w1/w2 still read exactly once across the grid.
__global__ __launch_bounds__(256) void k_s2a(const float* __restrict__ w1,
                                             const float* __restrict__ w2,
                                             const float* __restrict__ xs,
                                             float* __restrict__ part) {
    const int isp = blockIdx.x;             // 0..3
    const int og  = blockIdx.y;             // 0..15
    const int h   = blockIdx.z;
    const int m    = threadIdx.x & 63;
    const int osub = threadIdx.x >> 6;      // 0..3
    const int o = og * 4 + osub;
    const int i0 = isp * 16;

    float re[8], im[8];
    #pragma unroll
    for (int b = 0; b < 8; ++b) { re[b] = 0.f; im[b] = 0.f; }

    const float2* xsf = reinterpret_cast<const float2*>(xs);
    const float* w1p = w1 + (size_t)h * NE * NE * NM + (size_t)i0 * NE * NM + (size_t)o * NM + m;
    const float* w2p = w2 + (size_t)h * NE * NE * NM + (size_t)i0 * NE * NM + (size_t)o * NM + m;

    #pragma unroll 4
    for (int ii = 0; ii < 16; ++ii) {
        const int i = i0 + ii;
        float wr = w1p[(size_t)ii * (NE * NM)];
        float wi = w2p[(size_t)ii * (NE * NM)];
        #pragma unroll
        for (int b = 0; b < 8; ++b) {
            float2 xv = xsf[((size_t)(b * 8 + h) * 64 + i) * 64 + m];  // (re, im)
            re[b] = fmaf(xv.x, wr, fmaf(-xv.y, wi, re[b]));
            im[b] = fmaf(xv.x, wi, fmaf( xv.y, wr, im[b]));
        }
    }

    // part[isp][b][c][m] complex, c = h*64+o. Coalesced: m fastest.
    const int c = h * 64 + o;
    float2* pp = reinterpret_cast<float2*>(part);
    #pragma unroll
    for (int b = 0; b < 8; ++b)
        pp[(((size_t)isp * 8 + b) * 512 + c) * 64 + m] = make_float2(re[b], im[b]);
}

// Stage 2b: reduce 4 i-partials, apply irfft fold, pack bf16 G A-fragments.
// 262144 threads: e -> m (fast), c, b. One u32 store per thread.
__global__ __launch_bounds__(256) void k_s2red(const float* __restrict__ part,
                                               unsigned short* __restrict__ gf) {
    const int e = blockIdx.x * 256 + threadIdx.x;    // 0..262143
    const int m = e & 63;
    const int c = (e >> 6) & 511;
    const int b = e >> 15;

    const float2* pp = reinterpret_cast<const float2*>(part);
    float re = 0.f, im = 0.f;
    #pragma unroll
    for (int is = 0; is < 4; ++is) {
        float2 v = pp[(((size_t)is * 8 + b) * 512 + c) * 64 + m];
        re += v.x; im += v.y;
    }

    const float s = (m == 0 ? 1.0f : 2.0f) / (float)LN;  // (2-delta_m0)/L fold
    // G[2m][c]=s*re, G[2m+1][c]=-s*im into A-fragment layout:
    // slot = ((b*4 + (m>>4))*32 + (c>>4))*64 + ((m&15)>>2)*16 + (c&15), elems ((m&3)<<1)+{0,1}
    const int kk  = m >> 4;
    const int khi = ((m & 15) >> 2) * 16;
    const int jj  = (m & 3) << 1;
    size_t slot = (((size_t)b * 4 + kk) * 32 + (c >> 4)) * 64 + khi + (c & 15);
    unsigned int pk = (unsigned)bf16bits(re * s) | ((unsigned)bf16bits(-im * s) << 16);
    *reinterpret_cast<unsigned int*>(gf + slot * 8 + jj) = pk;
}

// Stage 3 MFMA: per b: out[l][c] = sum_mp T[l][mp] * G[mp][c].  M=c(128/block), N=l(64/block), K=128.
// grid (64 lb, 4 cb, 8 b), block 256 = 4 waves; wave w owns c-quarter [w*32, w*32+32).
// Zero LDS / zero barriers; both operand tables stream from L2.
__global__ __launch_bounds__(256, 2) void k_s3(const unsigned short* __restrict__ gf,
                                               const unsigned short* __restrict__ tfp,
                                               float* __restrict__ out) {
    const int lb = blockIdx.x;   // l base = lb*64
    const int cb = blockIdx.y;   // c base = cb*128
    const int b  = blockIdx.z;
    const int tid = threadIdx.x;
    const int w = tid >> 6, lane = tid & 63;

    const unsigned short* ga = gf + ((((size_t)b * 4) * 32 + cb * 8 + w * 2) * 64 + lane) * 8;
    const unsigned short* tb = tfp + (((size_t)lb * 4) * 64 + lane) * 8;

    f32x4 acc[2][4] = {};
    s16x8 af[3][2], bf[3][4];

#define S3_LOAD(T, SLOT)                                                          \
    {                                                                             \
        const unsigned short* gp_ = ga + (size_t)(T) * (32 * 64 * 8);             \
        const unsigned short* tp_ = tb + (size_t)(T) * (256 * 64 * 8);            \
        af[SLOT][0] = *reinterpret_cast<const s16x8*>(gp_);                       \
        af[SLOT][1] = *reinterpret_cast<const s16x8*>(gp_ + 64 * 8);              \
        bf[SLOT][0] = *reinterpret_cast<const s16x8*>(tp_);                       \
        bf[SLOT][1] = *reinterpret_cast<const s16x8*>(tp_ + 64 * 8);              \
        bf[SLOT][2] = *reinterpret_cast<const s16x8*>(tp_ + 2 * 64 * 8);          \
        bf[SLOT][3] = *reinterpret_cast<const s16x8*>(tp_ + 3 * 64 * 8);          \
    }

    S3_LOAD(0, 0)
    S3_LOAD(1, 1)

    #pragma unroll
    for (int t = 0; t < 4; ++t) {
        const int slot = t % 3;
        if (t + 2 < 4) { const int ns = (t + 2) % 3; S3_LOAD(t + 2, ns) }
        #pragma unroll
        for (int mi = 0; mi < 2; ++mi)
            #pragma unroll
            for (int ni = 0; ni < 4; ++ni)
                acc[mi][ni] = __builtin_amdgcn_mfma_f32_16x16x32_bf16(
                    af[slot][mi], bf[slot][ni], acc[mi][ni], 0, 0, 0);
    }
#undef S3_LOAD

    // D[row=c_local][col=l_local]; f32x4 regs span 4 consecutive c.
    const int c0 = cb * 128 + w * 32 + (lane >> 4) * 4;
    const int l0 = lb * 64 + (lane & 15);
    #pragma unroll
    for (int mi = 0; mi < 2; ++mi)
        #pragma unroll
        for (int ni = 0; ni < 4; ++ni) {
            float* op = out + ((size_t)b * LN + l0 + ni * 16) * NC + c0 + mi * 16;
            *reinterpret_cast<f32x4*>(op) = acc[mi][ni];
        }
}

extern "C" void kernel_launch(void* const* d_in, const int* in_sizes, int n_in,
                              void* d_out, int out_size, void* d_ws, size_t ws_size,
                              hipStream_t stream) {
    const float* q  = (const float*)d_in[0];
    // d_in[1] (k) and d_in[2] (v) are unused by the reference
    const float* w1 = (const float*)d_in[3];
    const float* w2 = (const float*)d_in[4];
    float* out = (float*)d_out;
    float* ws  = (float*)d_ws;

    unsigned short* egf = (unsigned short*)(ws + WS_EGF);
    unsigned short* tfp = (unsigned short*)(ws + WS_TF);
    unsigned short* gf  = (unsigned short*)(ws + WS_GF);
    float*          xp  = ws + WS_XP;
    float*          xs  = ws + WS_XS;
    float*          part = ws + WS_PART;

    k_tables<<<512, 256, 0, stream>>>(egf, tfp);
    k_fs1<<<dim3(8, NH, NB), 256, 0, stream>>>(q, egf, xp);
    k_presum<<<2048, 256, 0, stream>>>(xp, xs);
    k_s2a<<<dim3(4, 16, NH), 256, 0, stream>>>(w1, w2, xs, part);
    k_s2red<<<1024, 256, 0, stream>>>(part, gf);
    k_s3<<<dim3(64, 4, NB), 256, 0, stream>>>(gf, tfp, out);
}

// Round 6
// 66.154 us; speedup vs baseline: 1.9170x; 1.2992x over previous
//
#include <hip/hip_runtime.h>
#include <hip/hip_bf16.h>
#include <math.h>

// Problem constants
#define NB 8
#define LN 4096       // sequence length L
#define NH 8
#define NE 64
#define NC 512        // NH*NE channels
#define NM 64         // modes kept
#define LMASK 4095

typedef short s16x8 __attribute__((ext_vector_type(8)));
typedef float f32x4 __attribute__((ext_vector_type(4)));

// ws layout (in floats):
//  egf : bf16[128kc][8mt][64][8]        @ 0        (1 MB)  fwd twiddle A-fragments
//  tf  : bf16[4kk][256lt][64][8]        @ 262144   (1 MB)  inv twiddle B-fragments
//  gf  : bf16[8b][4kk][32ct][64][8]     @ 524288   (1 MB)  mixed-spectrum A-fragments
//  xp  : f32[8ks][8b][8h][64i][128m±]   @ 786432   (16 MB) partial fwd GEMM outputs
//  xs  : f32[8b][8h][64i][128m±]        @ 4980736  (2 MB)  ks-summed spectrum
//  part: f32[4is][8b][512c][64m][2]     @ 5505024  (8 MB)  stage2 i-split partials
#define WS_EGF 0
#define WS_TF  262144
#define WS_GF  524288
#define WS_XP  786432
#define WS_XS  4980736
#define WS_PART 5505024

static __device__ __forceinline__ unsigned short bf16bits(float f) {
    __hip_bfloat16 b = __float2bfloat16(f);
    return *reinterpret_cast<unsigned short*>(&b);
}

// Both twiddle tables in one launch. Blocks 0..255: egf (fwd A-frags);
// blocks 256..511: tf (inv B-frags).
__global__ __launch_bounds__(256) void k_tables(unsigned short* __restrict__ egf,
                                                unsigned short* __restrict__ tfp) {
    const int bid = blockIdx.x;
    const int s = (bid & 255) * 256 + threadIdx.x;   // 0..65535
    const int lane = s & 63;
    unsigned short v[8];
    if (bid < 256) {
        // E[2m][l]=cos, E[2m+1][l]=-sin ; slot s=(kc<<9)|(mt<<6)|lane
        int mt = (s >> 6) & 7, kc = s >> 9;
        int r = lane & 15, kg = lane >> 4;
        int mpm = mt * 16 + r;
        int m = mpm >> 1, isim = mpm & 1;
        #pragma unroll
        for (int j = 0; j < 8; ++j) {
            int l = kc * 32 + kg * 8 + j;
            int tw = (m * l) & LMASK;
            float ang = (6.283185307179586f / 4096.0f) * (float)tw;
            v[j] = bf16bits(isim ? -sinf(ang) : cosf(ang));
        }
    } else {
        // T[l][2m]=cos, T[l][2m+1]=sin ; slot s=(kk<<14)|(lt<<6)|lane
        int lt = (s >> 6) & 255, kk = s >> 14;
        int l = lt * 16 + (lane & 15);
        int khi = (lane >> 4) * 8;
        #pragma unroll
        for (int j = 0; j < 8; ++j) {
            int mp = kk * 32 + khi + j;
            int m = mp >> 1;
            int tw = (m * l) & LMASK;
            float ang = (6.283185307179586f / 4096.0f) * (float)tw;
            v[j] = bf16bits((mp & 1) ? sinf(ang) : cosf(ang));
        }
    }
    uint4 pk;
    pk.x = (unsigned)v[0] | ((unsigned)v[1] << 16);
    pk.y = (unsigned)v[2] | ((unsigned)v[3] << 16);
    pk.z = (unsigned)v[4] | ((unsigned)v[5] << 16);
    pk.w = (unsigned)v[6] | ((unsigned)v[7] << 16);
    unsigned short* dst = (bid < 256) ? egf : tfp;
    *reinterpret_cast<uint4*>(dst + (size_t)s * 8) = pk;
}

// Fused stage 1 (v2): zero LDS, zero barriers. Wave w owns i-subtile [w*16, w*16+16);
// q B-fragments gathered directly from global (8 dword loads/iter, 64B segments),
// egf A-fragments streamed from L2; both double-buffered. 8 MFMA/iter, 16 iters.
// grid (8 ks, 8 h, 8 b), block 256 = 4 waves.
__global__ __launch_bounds__(256, 2) void k_fs1(const float* __restrict__ q,
                                                const unsigned short* __restrict__ egf,
                                                float* __restrict__ xp) {
    const int ks = blockIdx.x, h = blockIdx.y, b = blockIdx.z;
    const int tid = threadIdx.x;
    const int w = tid >> 6, lane = tid & 63;
    const int i = w * 16 + (lane & 15);
    const int lrow = (lane >> 4) * 8;    // base l-offset within the 32-l step

    // q element j of iter t: q[b][ks*512 + t*32 + lrow + j][h][i]
    const float* qb = q + (((size_t)b * LN + (size_t)ks * 512 + lrow) * NH + h) * NE + i;
    // egf slot: ((kc*8 + mt)*64 + lane)*8, kc = ks*16 + t
    const unsigned short* eb = egf + ((size_t)(ks * 16) * 8 * 64 + lane) * 8;

    f32x4 acc[8];
    #pragma unroll
    for (int mt = 0; mt < 8; ++mt) acc[mt] = (f32x4)(0.0f);

    float qv[2][8];
    s16x8 af[2][8];

#define FS1_LOAD(T, S)                                                            \
    {                                                                             \
        const float* qp_ = qb + (size_t)(T) * 32 * NC;                            \
        _Pragma("unroll")                                                         \
        for (int j = 0; j < 8; ++j) qv[S][j] = qp_[(size_t)j * NC];               \
        const unsigned short* ep_ = eb + (size_t)(T) * (8 * 64 * 8);              \
        _Pragma("unroll")                                                         \
        for (int mt = 0; mt < 8; ++mt)                                            \
            af[S][mt] = *reinterpret_cast<const s16x8*>(ep_ + (size_t)mt * 512);  \
    }

    FS1_LOAD(0, 0)

    #pragma unroll
    for (int t = 0; t < 16; ++t) {
        const int cur = t & 1;
        if (t < 15) { const int nxt = cur ^ 1; FS1_LOAD(t + 1, nxt) }
        s16x8 bfr;
        #pragma unroll
        for (int j = 0; j < 8; ++j) bfr[j] = (short)bf16bits(qv[cur][j]);
        #pragma unroll
        for (int mt = 0; mt < 8; ++mt)
            acc[mt] = __builtin_amdgcn_mfma_f32_16x16x32_bf16(af[cur][mt], bfr, acc[mt], 0, 0, 0);
    }
#undef FS1_LOAD

    // Epilogue: D row = m±-local = (lane>>4)*4 + reg, col = i-local = lane&15.
    float* xpb = xp + ((size_t)ks * 64 + b * 8 + h) * (64 * 128) + (size_t)i * 128 + (lane >> 4) * 4;
    #pragma unroll
    for (int mt = 0; mt < 8; ++mt)
        *reinterpret_cast<f32x4*>(xpb + mt * 16) = acc[mt];
}

// Sum the 8 K-split partials (float4-vectorized; same per-element order).
__global__ __launch_bounds__(256) void k_presum(const float* __restrict__ xp,
                                                float* __restrict__ xs) {
    int e4 = blockIdx.x * 256 + threadIdx.x;     // 0..131071 float4s
    const f32x4* xp4 = reinterpret_cast<const f32x4*>(xp);
    f32x4 s = (f32x4)(0.0f);
    #pragma unroll
    for (int ks = 0; ks < 8; ++ks) s += xp4[(size_t)ks * 131072 + e4];
    reinterpret_cast<f32x4*>(xs)[e4] = s;
}

// Stage 2a (v2): LDS-staged channel mix. grid (4 isp, 8 og, 8 h), block 256.
// Block stages xs slice [8b][16i][64m] (64KB f32) once, coalesced; the o-loop
// then runs from LDS. w1/w2 read exactly once across the grid.
__global__ __launch_bounds__(256) void k_s2a(const float* __restrict__ w1,
                                             const float* __restrict__ w2,
                                             const float* __restrict__ xs,
                                             float* __restrict__ part) {
    __shared__ float2 sxs[8][16][64];       // [b][ii][m], 64 KB
    const int isp = blockIdx.x;             // 0..3 -> i0 = isp*16
    const int og  = blockIdx.y;             // 0..7 -> o0 = og*8
    const int h   = blockIdx.z;
    const int tt  = threadIdx.x;
    const int i0  = isp * 16;

    // stage: per b, 2048 contiguous floats = 512 float4
    {
        float4* dst = reinterpret_cast<float4*>(&sxs[0][0][0]);
        #pragma unroll
        for (int b = 0; b < 8; ++b) {
            const float4* s4 = reinterpret_cast<const float4*>(
                xs + (((size_t)(b * 8 + h)) * 64 + i0) * 128);
            dst[b * 512 + tt]       = s4[tt];
            dst[b * 512 + 256 + tt] = s4[256 + tt];
        }
    }
    __syncthreads();

    const int m    = tt & 63;
    const int osub = tt >> 6;               // 0..3
    const int o0   = og * 8 + osub * 2;     // 2 o per thread

    float re[2][8], im[2][8];
    #pragma unroll
    for (int oo = 0; oo < 2; ++oo)
        #pragma unroll
        for (int b = 0; b < 8; ++b) { re[oo][b] = 0.f; im[oo][b] = 0.f; }

    const float* w1p = w1 + (((size_t)h * NE + i0) * NE + o0) * NM + m;
    const float* w2p = w2 + (((size_t)h * NE + i0) * NE + o0) * NM + m;

    #pragma unroll 2
    for (int ii = 0; ii < 16; ++ii) {
        float wr0 = w1p[(size_t)ii * (NE * NM)];
        float wi0 = w2p[(size_t)ii * (NE * NM)];
        float wr1 = w1p[(size_t)ii * (NE * NM) + NM];
        float wi1 = w2p[(size_t)ii * (NE * NM) + NM];
        #pragma unroll
        for (int b = 0; b < 8; ++b) {
            float2 xv = sxs[b][ii][m];
            re[0][b] = fmaf(xv.x, wr0, fmaf(-xv.y, wi0, re[0][b]));
            im[0][b] = fmaf(xv.x, wi0, fmaf( xv.y, wr0, im[0][b]));
            re[1][b] = fmaf(xv.x, wr1, fmaf(-xv.y, wi1, re[1][b]));
            im[1][b] = fmaf(xv.x, wi1, fmaf( xv.y, wr1, im[1][b]));
        }
    }

    // part[isp][b][c][m] complex, c = h*64 + o. m fastest -> coalesced.
    float2* pp = reinterpret_cast<float2*>(part);
    #pragma unroll
    for (int oo = 0; oo < 2; ++oo) {
        const int c = h * 64 + o0 + oo;
        #pragma unroll
        for (int b = 0; b < 8; ++b)
            pp[(((size_t)isp * 8 + b) * 512 + c) * 64 + m] = make_float2(re[oo][b], im[oo][b]);
    }
}

// Stage 2b: reduce 4 i-partials, apply irfft fold, pack bf16 G A-fragments.
// 262144 threads: e -> m (fast), c, b. One u32 store per thread.
__global__ __launch_bounds__(256) void k_s2red(const float* __restrict__ part,
                                               unsigned short* __restrict__ gf) {
    const int e = blockIdx.x * 256 + threadIdx.x;    // 0..262143
    const int m = e & 63;
    const int c = (e >> 6) & 511;
    const int b = e >> 15;

    const float2* pp = reinterpret_cast<const float2*>(part);
    float re = 0.f, im = 0.f;
    #pragma unroll
    for (int is = 0; is < 4; ++is) {
        float2 v = pp[(((size_t)is * 8 + b) * 512 + c) * 64 + m];
        re += v.x; im += v.y;
    }

    const float s = (m == 0 ? 1.0f : 2.0f) / (float)LN;  // (2-delta_m0)/L fold
    // G[2m][c]=s*re, G[2m+1][c]=-s*im into A-fragment layout:
    // slot = ((b*4 + (m>>4))*32 + (c>>4))*64 + ((m&15)>>2)*16 + (c&15), elems ((m&3)<<1)+{0,1}
    const int kk  = m >> 4;
    const int khi = ((m & 15) >> 2) * 16;
    const int jj  = (m & 3) << 1;
    size_t slot = (((size_t)b * 4 + kk) * 32 + (c >> 4)) * 64 + khi + (c & 15);
    unsigned int pk = (unsigned)bf16bits(re * s) | ((unsigned)bf16bits(-im * s) << 16);
    *reinterpret_cast<unsigned int*>(gf + slot * 8 + jj) = pk;
}

// Stage 3 MFMA: per b: out[l][c] = sum_mp T[l][mp] * G[mp][c].  M=c(128/block), N=l(64/block), K=128.
// grid (64 lb, 4 cb, 8 b), block 256 = 4 waves; wave w owns c-quarter [w*32, w*32+32).
// Zero LDS / zero barriers; both operand tables stream from L2.
__global__ __launch_bounds__(256, 2) void k_s3(const unsigned short* __restrict__ gf,
                                               const unsigned short* __restrict__ tfp,
                                               float* __restrict__ out) {
    const int lb = blockIdx.x;   // l base = lb*64
    const int cb = blockIdx.y;   // c base = cb*128
    const int b  = blockIdx.z;
    const int tid = threadIdx.x;
    const int w = tid >> 6, lane = tid & 63;

    const unsigned short* ga = gf + ((((size_t)b * 4) * 32 + cb * 8 + w * 2) * 64 + lane) * 8;
    const unsigned short* tb = tfp + (((size_t)lb * 4) * 64 + lane) * 8;

    f32x4 acc[2][4] = {};
    s16x8 af[3][2], bf[3][4];

#define S3_LOAD(T, SLOT)                                                          \
    {                                                                             \
        const unsigned short* gp_ = ga + (size_t)(T) * (32 * 64 * 8);             \
        const unsigned short* tp_ = tb + (size_t)(T) * (256 * 64 * 8);            \
        af[SLOT][0] = *reinterpret_cast<const s16x8*>(gp_);                       \
        af[SLOT][1] = *reinterpret_cast<const s16x8*>(gp_ + 64 * 8);              \
        bf[SLOT][0] = *reinterpret_cast<const s16x8*>(tp_);                       \
        bf[SLOT][1] = *reinterpret_cast<const s16x8*>(tp_ + 64 * 8);              \
        bf[SLOT][2] = *reinterpret_cast<const s16x8*>(tp_ + 2 * 64 * 8);          \
        bf[SLOT][3] = *reinterpret_cast<const s16x8*>(tp_ + 3 * 64 * 8);          \
    }

    S3_LOAD(0, 0)
    S3_LOAD(1, 1)

    #pragma unroll
    for (int t = 0; t < 4; ++t) {
        const int slot = t % 3;
        if (t + 2 < 4) { const int ns = (t + 2) % 3; S3_LOAD(t + 2, ns) }
        #pragma unroll
        for (int mi = 0; mi < 2; ++mi)
            #pragma unroll
            for (int ni = 0; ni < 4; ++ni)
                acc[mi][ni] = __builtin_amdgcn_mfma_f32_16x16x32_bf16(
                    af[slot][mi], bf[slot][ni], acc[mi][ni], 0, 0, 0);
    }
#undef S3_LOAD

    // D[row=c_local][col=l_local]; f32x4 regs span 4 consecutive c.
    const int c0 = cb * 128 + w * 32 + (lane >> 4) * 4;
    const int l0 = lb * 64 + (lane & 15);
    #pragma unroll
    for (int mi = 0; mi < 2; ++mi)
        #pragma unroll
        for (int ni = 0; ni < 4; ++ni) {
            float* op = out + ((size_t)b * LN + l0 + ni * 16) * NC + c0 + mi * 16;
            *reinterpret_cast<f32x4*>(op) = acc[mi][ni];
        }
}

extern "C" void kernel_launch(void* const* d_in, const int* in_sizes, int n_in,
                              void* d_out, int out_size, void* d_ws, size_t ws_size,
                              hipStream_t stream) {
    const float* q  = (const float*)d_in[0];
    // d_in[1] (k) and d_in[2] (v) are unused by the reference
    const float* w1 = (const float*)d_in[3];
    const float* w2 = (const float*)d_in[4];
    float* out = (float*)d_out;
    float* ws  = (float*)d_ws;

    unsigned short* egf = (unsigned short*)(ws + WS_EGF);
    unsigned short* tfp = (unsigned short*)(ws + WS_TF);
    unsigned short* gf  = (unsigned short*)(ws + WS_GF);
    float*          xp  = ws + WS_XP;
    float*          xs  = ws + WS_XS;
    float*          part = ws + WS_PART;

    k_tables<<<512, 256, 0, stream>>>(egf, tfp);
    k_fs1<<<dim3(8, NH, NB), 256, 0, stream>>>(q, egf, xp);
    k_presum<<<512, 256, 0, stream>>>(xp, xs);
    k_s2a<<<dim3(4, 8, NH), 256, 0, stream>>>(w1, w2, xs, part);
    k_s2red<<<1024, 256, 0, stream>>>(part, gf);
    k_s3<<<dim3(64, 4, NB), 256, 0, stream>>>(gf, tfp, out);
}